// Round 1
// baseline (376.228 us; speedup 1.0000x reference)
//
#include <hip/hip_runtime.h>

// Luong attention: enc [B,Te,D] f32, dec [B,Td,D] f32
// score[b,e,t] = enc[b,e,:]·dec[b,t,:]; attn = softmax over e;
// context[b,t,:] = sum_e attn[b,e,t] * enc[b,e,:]
// out[b,t,:] = concat(dec[b,t,:], context[b,t,:])  -> [B,Td,2D] f32
//
// Flash-attention style. QK^T uses bf16 hi/lo split (3 MFMAs) for ~f32
// accuracy; PV uses bf16 (P in [0,1], error ~0.005 << 0.104 threshold).

#define B_   8
#define TE   2048
#define TD   2048
#define D_   256
#define KBLK 64
#define QBLK 64   // per block (4 waves x 16 rows)

typedef __bf16 bf16x8 __attribute__((ext_vector_type(8)));
typedef unsigned short u16x8 __attribute__((ext_vector_type(8)));
typedef float f32x4 __attribute__((ext_vector_type(4)));

__device__ __forceinline__ unsigned f2bf_bits(float f) {
  unsigned u = __builtin_bit_cast(unsigned, f);
  return (u + 0x7FFFu + ((u >> 16) & 1u)) >> 16;   // RTNE
}
__device__ __forceinline__ float bf_to_f(unsigned bits) {
  return __builtin_bit_cast(float, bits << 16);
}

__global__ __launch_bounds__(256, 1) void luong_attn(
    const float* __restrict__ enc, const float* __restrict__ dec,
    float* __restrict__ out) {
  extern __shared__ char lds[];
  char* Khi = lds;            // 64 rows * 512B (bf16 hi of K-tile), swizzled
  char* Klo = lds + 32768;    // 64 rows * 512B (bf16 lo)
  char* Vt  = lds + 65536;    // 256 rows * 128B (bf16 enc^T tile), swizzled

  const int tid  = threadIdx.x;
  const int wave = tid >> 6;
  const int lane = tid & 63;
  const int g = lane >> 4;    // 0..3
  const int c = lane & 15;    // 0..15

  const int nQB = TD / QBLK;                 // 32
  const int b   = blockIdx.x / nQB;
  const int q0  = (blockIdx.x % nQB) * QBLK;
  const int t   = q0 + wave * 16 + c;        // this lane's output column t

  const float* encB = enc + (size_t)b * TE * D_;
  const float* decB = dec + (size_t)b * TD * D_;
  float* outB = out + (size_t)b * TD * (2 * D_);

  // ---- Q fragments (hi/lo bf16), reused over all K-tiles ----
  // B-operand layout: lane holds Q[t][dc*32 + 8g + j], j=0..7
  bf16x8 qhi[8], qlo[8];
  {
    const float* qrow = decB + (size_t)t * D_;
#pragma unroll
    for (int dc = 0; dc < 8; ++dc) {
      const float4 v0 = *(const float4*)(qrow + dc * 32 + 8 * g);
      const float4 v1 = *(const float4*)(qrow + dc * 32 + 8 * g + 4);
      float f[8] = {v0.x, v0.y, v0.z, v0.w, v1.x, v1.y, v1.z, v1.w};
      u16x8 h, l;
#pragma unroll
      for (int j = 0; j < 8; ++j) {
        unsigned hb = f2bf_bits(f[j]);
        h[j] = (unsigned short)hb;
        l[j] = (unsigned short)f2bf_bits(f[j] - bf_to_f(hb));
      }
      qhi[dc] = __builtin_bit_cast(bf16x8, h);
      qlo[dc] = __builtin_bit_cast(bf16x8, l);
    }
  }

  float m_run = -INFINITY, l_run = 0.f;
  f32x4 ctx[16];
#pragma unroll
  for (int i = 0; i < 16; ++i) ctx[i] = (f32x4){0.f, 0.f, 0.f, 0.f};

  for (int kt = 0; kt < TE / KBLK; ++kt) {
    __syncthreads();   // previous compute done before overwriting LDS
    const float* src = encB + (size_t)kt * KBLK * D_;
    // ---- stage K hi/lo (row-major, swizzled) ----
#pragma unroll
    for (int i = 0; i < 16; ++i) {
      int ci = tid + 256 * i;          // 0..4095
      int e  = ci >> 6;                // 0..63
      int d4 = (ci & 63) << 2;         // 0..252
      float4 v = *(const float4*)(src + (size_t)e * D_ + d4);
      float f[4] = {v.x, v.y, v.z, v.w};
      unsigned short h[4], lo[4];
#pragma unroll
      for (int j = 0; j < 4; ++j) {
        unsigned hb = f2bf_bits(f[j]);
        h[j]  = (unsigned short)hb;
        lo[j] = (unsigned short)f2bf_bits(f[j] - bf_to_f(hb));
      }
      int bo = e * 512 + ((d4 * 2) ^ ((e & 7) << 4));
      *(ushort4*)(Khi + bo) = make_ushort4(h[0], h[1], h[2], h[3]);
      *(ushort4*)(Klo + bo) = make_ushort4(lo[0], lo[1], lo[2], lo[3]);
    }
    // ---- stage V^T (bf16 hi of enc^T, swizzled); re-read from global,
    // coalesced across lanes (consecutive d) ----
#pragma unroll
    for (int i = 0; i < 8; ++i) {
      int d  = tid;                    // 0..255
      const float* col = src + (size_t)(i * 8) * D_ + d;
      u16x8 h;
#pragma unroll
      for (int j = 0; j < 8; ++j) h[j] = (unsigned short)f2bf_bits(col[(size_t)j * D_]);
      int bo = d * 128 + ((i * 16) ^ ((d & 7) << 4));
      *(u16x8*)(Vt + bo) = h;
    }
    __syncthreads();

    // ---- QK^T swapped: S^T[e][t] tiles (4 tiles of 16 e) ----
    f32x4 sT[4];
#pragma unroll
    for (int ta = 0; ta < 4; ++ta) sT[ta] = (f32x4){0.f, 0.f, 0.f, 0.f};
#pragma unroll
    for (int dc = 0; dc < 8; ++dc) {
#pragma unroll
      for (int ta = 0; ta < 4; ++ta) {
        int e  = ta * 16 + c;
        int bo = e * 512 + ((dc * 64 + 16 * g) ^ ((e & 7) << 4));
        bf16x8 kh = *(const bf16x8*)(Khi + bo);
        bf16x8 kl = *(const bf16x8*)(Klo + bo);
        sT[ta] = __builtin_amdgcn_mfma_f32_16x16x32_bf16(kh, qhi[dc], sT[ta], 0, 0, 0);
        sT[ta] = __builtin_amdgcn_mfma_f32_16x16x32_bf16(kh, qlo[dc], sT[ta], 0, 0, 0);
        sT[ta] = __builtin_amdgcn_mfma_f32_16x16x32_bf16(kl, qhi[dc], sT[ta], 0, 0, 0);
      }
    }

    // ---- online softmax over e (C-layout: lane owns e = ta*16+4g+r, col c) ----
    float vmax = -INFINITY;
#pragma unroll
    for (int ta = 0; ta < 4; ++ta)
#pragma unroll
      for (int r = 0; r < 4; ++r) vmax = fmaxf(vmax, sT[ta][r]);
    vmax = fmaxf(vmax, __shfl_xor(vmax, 16, 64));
    vmax = fmaxf(vmax, __shfl_xor(vmax, 32, 64));
    float m_new = fmaxf(m_run, vmax);
    float alpha = __expf(m_run - m_new);
    float psum = 0.f;
    unsigned w0[4], w1[4];
#pragma unroll
    for (int ta = 0; ta < 4; ++ta) {
      float p0 = __expf(sT[ta][0] - m_new);
      float p1 = __expf(sT[ta][1] - m_new);
      float p2 = __expf(sT[ta][2] - m_new);
      float p3 = __expf(sT[ta][3] - m_new);
      psum += (p0 + p1) + (p2 + p3);
      w0[ta] = f2bf_bits(p0) | (f2bf_bits(p1) << 16);
      w1[ta] = f2bf_bits(p2) | (f2bf_bits(p3) << 16);
    }
    psum += __shfl_xor(psum, 16, 64);
    psum += __shfl_xor(psum, 32, 64);
    l_run = l_run * alpha + psum;
    m_run = m_new;
#pragma unroll
    for (int i = 0; i < 16; ++i) ctx[i] *= alpha;

    // ---- PV: ctx^T += enc^T * P^T, K-chunks of 32 e ----
#pragma unroll
    for (int kp = 0; kp < 2; ++kp) {
      const int A    = 2 * (g & 1);
      const int srcA = A * 16 + c;
      const int srcB = srcA + 16;
      const int tl0  = 2 * kp, tl1 = 2 * kp + 1;
      unsigned y0 = (unsigned)__shfl((int)w0[tl0], srcA, 64);
      unsigned y1 = (unsigned)__shfl((int)w1[tl0], srcA, 64);
      unsigned y2 = (unsigned)__shfl((int)w0[tl0], srcB, 64);
      unsigned y3 = (unsigned)__shfl((int)w1[tl0], srcB, 64);
      unsigned z0 = (unsigned)__shfl((int)w0[tl1], srcA, 64);
      unsigned z1 = (unsigned)__shfl((int)w1[tl1], srcA, 64);
      unsigned z2 = (unsigned)__shfl((int)w0[tl1], srcB, 64);
      unsigned z3 = (unsigned)__shfl((int)w1[tl1], srcB, 64);
      bool hiT = (g >> 1) & 1;
      int4 bi = hiT ? make_int4((int)z0, (int)z1, (int)z2, (int)z3)
                    : make_int4((int)y0, (int)y1, (int)y2, (int)y3);
      bf16x8 bfrag = __builtin_bit_cast(bf16x8, bi);
#pragma unroll
      for (int dt = 0; dt < 16; ++dt) {
        int row = dt * 16 + c;
        int bo  = row * 128 + ((kp * 64 + 16 * g) ^ ((row & 7) << 4));
        bf16x8 af = *(const bf16x8*)(Vt + bo);
        ctx[dt] = __builtin_amdgcn_mfma_f32_16x16x32_bf16(af, bfrag, ctx[dt], 0, 0, 0);
      }
    }
  }

  // ---- epilogue: context / l into out[:, 256:512] ----
  float inv_l = 1.0f / l_run;
  float* orow = outB + (size_t)t * (2 * D_) + D_;
#pragma unroll
  for (int dt = 0; dt < 16; ++dt) {
    float4 v;
    v.x = ctx[dt][0] * inv_l;
    v.y = ctx[dt][1] * inv_l;
    v.z = ctx[dt][2] * inv_l;
    v.w = ctx[dt][3] * inv_l;
    *(float4*)(orow + dt * 16 + 4 * g) = v;
  }
  // ---- copy dec rows into out[:, 0:256] (coalesced) ----
#pragma unroll
  for (int i = 0; i < 16; ++i) {
    int ci = tid + 256 * i;
    int rr = ci >> 6;
    int d4 = (ci & 63) << 2;
    *(float4*)(outB + (size_t)(q0 + rr) * 512 + d4) =
        *(const float4*)(decB + (size_t)(q0 + rr) * 256 + d4);
  }
}

extern "C" void kernel_launch(void* const* d_in, const int* in_sizes, int n_in,
                              void* d_out, int out_size, void* d_ws, size_t ws_size,
                              hipStream_t stream) {
  const float* enc = (const float*)d_in[0];
  const float* dec = (const float*)d_in[1];
  float* out = (float*)d_out;
  (void)in_sizes; (void)n_in; (void)d_ws; (void)ws_size; (void)out_size;

  dim3 grid(B_ * (TD / QBLK));   // 256 blocks
  dim3 block(256);
  size_t ldsBytes = 98304;       // 96 KiB dynamic LDS
  luong_attn<<<grid, block, ldsBytes, stream>>>(enc, dec, out);
}

// Round 2
// 153.847 us; speedup vs baseline: 2.4455x; 2.4455x over previous
//
#include <hip/hip_runtime.h>

// Luong attention, flash-style, f16 MFMA path.
// enc [B,Te,D] f32, dec [B,Td,D] f32 -> out [B,Td,2D] f32 (concat(dec, context))
// Prepass 1: enc -> encK f16, chunk-swizzled within each 512B row (x ^= e&7)
// Prepass 2: enc -> encVt f16, tiled [b][e/32][d][32], chunk-swizzled (y ^= (d>>1)&3)
// Main: 512 thr = 8 waves = 2 e-groups x 4 t-waves; KBLK=32, double-buffered
//       global_load_lds staging; QK^T = K_f16 x (Q_hi + Q_lo) (2 MFMAs);
//       online softmax; PV f16; cross-group merge via LDS.

#define B_   8
#define TE   2048
#define TD   2048
#define D_   256
#define NIT  32   // (TE/2)/32 k-tiles per e-group

typedef _Float16 f16x8 __attribute__((ext_vector_type(8)));
typedef float f32x4 __attribute__((ext_vector_type(4)));

__device__ __forceinline__ unsigned pk2(float a, float b) {
  unsigned short ua = __builtin_bit_cast(unsigned short, (_Float16)a);
  unsigned short ub = __builtin_bit_cast(unsigned short, (_Float16)b);
  return (unsigned)ua | ((unsigned)ub << 16);
}

#define GLOAD16(gsrc, ldst)                                                  \
  __builtin_amdgcn_global_load_lds(                                          \
      (const __attribute__((address_space(1))) unsigned int*)(const void*)(gsrc), \
      (__attribute__((address_space(3))) unsigned int*)(void*)(ldst), 16, 0, 0)

// ---- prepass 1: enc f32 -> encK f16, swizzled chunks (16B chunk x of row e
// holds source chunk x ^ (e&7)) ----
__global__ __launch_bounds__(256) void prep_k(const float* __restrict__ enc,
                                              _Float16* __restrict__ out) {
  int idx = blockIdx.x * 256 + threadIdx.x;   // chunk index, 524288 total
  int row = idx >> 5, x = idx & 31;
  int xs = x ^ (row & 7);
  const float* src = enc + (size_t)row * 256 + xs * 8;
  float4 v0 = *(const float4*)src;
  float4 v1 = *(const float4*)(src + 4);
  f16x8 h;
  h[0] = (_Float16)v0.x; h[1] = (_Float16)v0.y; h[2] = (_Float16)v0.z; h[3] = (_Float16)v0.w;
  h[4] = (_Float16)v1.x; h[5] = (_Float16)v1.y; h[6] = (_Float16)v1.z; h[7] = (_Float16)v1.w;
  *(f16x8*)(out + (size_t)idx * 8) = h;
}

// ---- prepass 2: enc f32 -> encVt f16 tiled [b][ct=e/32][d][32], with chunk
// position y holding source e-chunk y ^ ((d>>1)&3) ----
__global__ __launch_bounds__(256) void prep_vt(const float* __restrict__ enc,
                                               _Float16* __restrict__ outT) {
  __shared__ float tile[64][65];
  int bid = blockIdx.x;                 // 8 * 32 * 4 = 1024
  int b = bid >> 7, r = bid & 127;
  int et = r >> 2, dt = r & 3;
  int e0 = et * 64, d0 = dt * 64;
  int tx = threadIdx.x & 63, ty = threadIdx.x >> 6;
  const float* src = enc + ((size_t)b * TE + e0) * D_ + d0;
#pragma unroll
  for (int i = 0; i < 16; ++i) {
    int e = i * 4 + ty;
    tile[e][tx] = src[(size_t)e * D_ + tx];
  }
  __syncthreads();
#pragma unroll
  for (int i = 0; i < 16; ++i) {
    int idx = i * 256 + threadIdx.x;    // 0..4095
    int d_loc = idx >> 6, eT = idx & 63;
    int d = d0 + d_loc;
    int ctl = eT >> 5, e32 = eT & 31;
    int y = e32 >> 3, j = e32 & 7;
    int ysrc = y ^ ((d >> 1) & 3);
    int esrc = ctl * 32 + ysrc * 8 + j;
    size_t o = (((size_t)b * 64 + (e0 >> 5) + ctl) * 256 + d) * 32 + e32;
    outT[o] = (_Float16)tile[esrc][d_loc];
  }
}

__global__ __launch_bounds__(512, 2) void luong_main(
    const _Float16* __restrict__ encK,   // [B][TE][256] swizzled
    const _Float16* __restrict__ encVt,  // [B][64][256][32] tiled/swizzled
    const float* __restrict__ dec,
    float* __restrict__ out) {
  extern __shared__ char lds[];
  const int tid = threadIdx.x;
  const int lane = tid & 63, wave = tid >> 6;
  const int wr = wave >> 2, wc = wave & 3;   // e-group, t-group
  const int g = lane >> 4, c = lane & 15;

  int bidl = (blockIdx.x & 7) * 32 + (blockIdx.x >> 3);  // XCD-contiguous batches
  const int b = bidl >> 5;
  const int q0 = (bidl & 31) * 64;
  const int t = q0 + wc * 16 + c;

  const float* decB = dec + (size_t)b * TD * D_;
  float* outB = out + (size_t)b * TD * (2 * D_);

  // ---- Q fragments f16 hi/lo ----
  f16x8 qh[8], ql[8];
  {
    const float* qrow = decB + (size_t)t * D_;
#pragma unroll
    for (int dc = 0; dc < 8; ++dc) {
      float4 v0 = *(const float4*)(qrow + dc * 32 + 8 * g);
      float4 v1 = *(const float4*)(qrow + dc * 32 + 8 * g + 4);
      float f[8] = {v0.x, v0.y, v0.z, v0.w, v1.x, v1.y, v1.z, v1.w};
      f16x8 H, L;
#pragma unroll
      for (int j = 0; j < 8; ++j) {
        _Float16 h = (_Float16)f[j];
        H[j] = h;
        L[j] = (_Float16)(f[j] - (float)h);
      }
      qh[dc] = H; ql[dc] = L;
    }
  }

  // ---- dec -> out[:, :256] copy (independent, issue early) ----
#pragma unroll
  for (int i = 0; i < 8; ++i) {
    int ci = tid + 512 * i;
    int rr = ci >> 6, d4 = (ci & 63) << 2;
    *(float4*)(outB + (size_t)(q0 + rr) * 512 + d4) =
        *(const float4*)(decB + (size_t)(q0 + rr) * 256 + d4);
  }

  const _Float16* kbase = encK + ((size_t)b * TE + wr * 1024) * D_;
  const _Float16* vbase = encVt + ((size_t)b * 64 + wr * 32) * 8192;

  auto STAGE = [&](int buf, int it) {
    char* Kd = lds + (size_t)(buf * 2 + wr) * 32768;
    char* Vd = Kd + 16384;
    const _Float16* ks = kbase + (size_t)it * 8192;
    const _Float16* vs = vbase + (size_t)it * 8192;
#pragma unroll
    for (int q = 0; q < 4; ++q) {
      int chunk = wc * 256 + q * 64 + lane;
      GLOAD16(ks + (size_t)chunk * 8, Kd + wc * 4096 + q * 1024);
      GLOAD16(vs + (size_t)chunk * 8, Vd + wc * 4096 + q * 1024);
    }
  };

  float m_run = -INFINITY, l_run = 0.f;
  f32x4 ctx[16];
#pragma unroll
  for (int i = 0; i < 16; ++i) ctx[i] = (f32x4){0.f, 0.f, 0.f, 0.f};

  STAGE(0, 0);
  __syncthreads();

  for (int it = 0; it < NIT; ++it) {
    int buf = it & 1;
    if (it + 1 < NIT) STAGE(buf ^ 1, it + 1);

    const char* Kb = lds + (size_t)(buf * 2 + wr) * 32768;
    const char* Vb = Kb + 16384;

    // ---- QK^T (swapped): S^T[e_loc][t], e_loc = ta*16 + 4g + r in C layout ----
    f32x4 sA = (f32x4){0.f, 0.f, 0.f, 0.f};
    f32x4 sB = (f32x4){0.f, 0.f, 0.f, 0.f};
    const int e0 = c, e1 = 16 + c;
#pragma unroll
    for (int dc = 0; dc < 8; ++dc) {
      int x = dc * 4 + g;
      f16x8 k0 = *(const f16x8*)(Kb + e0 * 512 + ((x ^ (e0 & 7)) << 4));
      f16x8 k1 = *(const f16x8*)(Kb + e1 * 512 + ((x ^ (e1 & 7)) << 4));
      sA = __builtin_amdgcn_mfma_f32_16x16x32_f16(k0, qh[dc], sA, 0, 0, 0);
      sA = __builtin_amdgcn_mfma_f32_16x16x32_f16(k0, ql[dc], sA, 0, 0, 0);
      sB = __builtin_amdgcn_mfma_f32_16x16x32_f16(k1, qh[dc], sB, 0, 0, 0);
      sB = __builtin_amdgcn_mfma_f32_16x16x32_f16(k1, ql[dc], sB, 0, 0, 0);
    }

    // ---- online softmax over the 32 e of this tile ----
    float vmax = fmaxf(fmaxf(fmaxf(sA[0], sA[1]), fmaxf(sA[2], sA[3])),
                       fmaxf(fmaxf(sB[0], sB[1]), fmaxf(sB[2], sB[3])));
    vmax = fmaxf(vmax, __shfl_xor(vmax, 16, 64));
    vmax = fmaxf(vmax, __shfl_xor(vmax, 32, 64));
    float m_new = fmaxf(m_run, vmax);
    float alpha = __expf(m_run - m_new);
    float p0 = __expf(sA[0] - m_new), p1 = __expf(sA[1] - m_new);
    float p2 = __expf(sA[2] - m_new), p3 = __expf(sA[3] - m_new);
    float p4 = __expf(sB[0] - m_new), p5 = __expf(sB[1] - m_new);
    float p6 = __expf(sB[2] - m_new), p7 = __expf(sB[3] - m_new);
    float ps = ((p0 + p1) + (p2 + p3)) + ((p4 + p5) + (p6 + p7));
    ps += __shfl_xor(ps, 16, 64);
    ps += __shfl_xor(ps, 32, 64);
    l_run = l_run * alpha + ps;
    m_run = m_new;
    unsigned w00 = pk2(p0, p1), w10 = pk2(p2, p3);
    unsigned w01 = pk2(p4, p5), w11 = pk2(p6, p7);
#pragma unroll
    for (int i = 0; i < 16; ++i) ctx[i] *= alpha;

    // ---- gather P B-fragment: lane needs P[8g+j][c], j=0..7 ----
    int srcA = (2 * (g & 1)) * 16 + c, srcB = srcA + 16;
    int y0 = __shfl((int)w00, srcA, 64), y1 = __shfl((int)w10, srcA, 64);
    int y2 = __shfl((int)w00, srcB, 64), y3 = __shfl((int)w10, srcB, 64);
    int z0 = __shfl((int)w01, srcA, 64), z1 = __shfl((int)w11, srcA, 64);
    int z2 = __shfl((int)w01, srcB, 64), z3 = __shfl((int)w11, srcB, 64);
    int4 bi = (g >> 1) ? make_int4(z0, z1, z2, z3) : make_int4(y0, y1, y2, y3);
    f16x8 bfrag = __builtin_bit_cast(f16x8, bi);

    // ---- PV: ctx^T += encT * P ----
#pragma unroll
    for (int dt = 0; dt < 16; ++dt) {
      int row = dt * 16 + c;
      f16x8 af = *(const f16x8*)(Vb + row * 64 + ((g ^ ((row >> 1) & 3)) << 4));
      ctx[dt] = __builtin_amdgcn_mfma_f32_16x16x32_f16(af, bfrag, ctx[dt], 0, 0, 0);
    }
    __syncthreads();
  }

  // ---- cross-group merge (2 e-groups) ----
  float* mlb = (float*)(lds + 69632);
  if (lane < 16) {
    mlb[((wr * 4 + wc) * 16 + c) * 2 + 0] = m_run;
    mlb[((wr * 4 + wc) * 16 + c) * 2 + 1] = l_run;
  }
  __syncthreads();
  float m_o = mlb[(((1 - wr) * 4 + wc) * 16 + c) * 2 + 0];
  float l_o = mlb[(((1 - wr) * 4 + wc) * 16 + c) * 2 + 1];
  float M = fmaxf(m_run, m_o);
  float fme = __expf(m_run - M);
  float L = l_run * fme + l_o * __expf(m_o - M);
  float invL = 1.0f / L;

  float* Xb = (float*)lds + wc * 4352;   // [256][17] f32 per t-group
  if (wr == 1) {
#pragma unroll
    for (int dt = 0; dt < 16; ++dt)
#pragma unroll
      for (int r = 0; r < 4; ++r) {
        int d = dt * 16 + 4 * g + r;
        Xb[d * 17 + c] = ctx[dt][r] * fme;
      }
  }
  __syncthreads();
  if (wr == 0) {
    float* orow = outB + (size_t)t * 512 + 256;
#pragma unroll
    for (int dt = 0; dt < 16; ++dt) {
      float4 v;
      float vv[4];
#pragma unroll
      for (int r = 0; r < 4; ++r) {
        int d = dt * 16 + 4 * g + r;
        vv[r] = (ctx[dt][r] * fme + Xb[d * 17 + c]) * invL;
      }
      v.x = vv[0]; v.y = vv[1]; v.z = vv[2]; v.w = vv[3];
      *(float4*)(orow + dt * 16 + 4 * g) = v;
    }
  }
}

extern "C" void kernel_launch(void* const* d_in, const int* in_sizes, int n_in,
                              void* d_out, int out_size, void* d_ws, size_t ws_size,
                              hipStream_t stream) {
  const float* enc = (const float*)d_in[0];
  const float* dec = (const float*)d_in[1];
  float* out = (float*)d_out;
  (void)in_sizes; (void)n_in; (void)out_size; (void)ws_size;

  _Float16* encK  = (_Float16*)d_ws;                           // 8 MiB
  _Float16* encVt = (_Float16*)((char*)d_ws + 8388608);        // 8 MiB

  prep_k<<<2048, 256, 0, stream>>>(enc, encK);
  prep_vt<<<1024, 256, 0, stream>>>(enc, encVt);
  luong_main<<<256, 512, 131072, stream>>>(encK, encVt, dec, out);
}